// Round 3
// baseline (401.894 us; speedup 1.0000x reference)
//
#include <hip/hip_runtime.h>

#define BLK 256
#define EPT 2
#define ELEMS (BLK * EPT)          // 512 elements per block

// Zero-LDS, zero-barrier version. Weights region (base misaligned by 3 floats
// relative to 16B) is written directly from registers: thread t owns global
// weight floats [16t+1 .. 16t+16] = 4 aligned float4 quads; the last slot of
// the 4th quad is w0 of the next thread's first element, fetched with one
// __shfl_down. Wave-boundary lanes (lane 63) store 3 scalars instead; lane 0
// stores its own head w0 scalar. Every float written exactly once.
__global__ __launch_bounds__(BLK) void fp4_kernel(
    const float* __restrict__ x,
    const float* __restrict__ delta_raw,
    const float* __restrict__ bounds_base,
    const float* __restrict__ values_table,
    float* __restrict__ out, long long N)
{
    const int tid = threadIdx.x;
    const long long base = (long long)blockIdx.x * ELEMS;
    const long long g0 = base + 2 * tid;

    // wave-uniform scalars (uniform addresses -> s_load; tanh folded to SGPR)
    float ht = 0.5f * tanhf(delta_raw[0]);
    ht = __int_as_float(__builtin_amdgcn_readfirstlane(__float_as_int(ht)));
    const float C = 14.426950408889634f;        // (1/TAU) * log2(e)
    float sb[7], cb[7];
#pragma unroll
    for (int j = 0; j < 7; ++j) { sb[j] = bounds_base[j] + ht; cb[j] = sb[j] * C; }
    float vt[8];
#pragma unroll
    for (int k = 0; k < 8; ++k) vt[k] = values_table[k];

    const float2 xv = *reinterpret_cast<const float2*>(x + g0);
    const float xe[EPT] = {xv.x, xv.y};

    // per-32-elem amax: local max of 2, butterfly over 16-lane group.
    // fmax exactly associative/commutative -> bit-identical to reference.
    float a = fmaxf(fabsf(xe[0]), fabsf(xe[1]));
    a = fmaxf(a, __shfl_xor(a, 1));
    a = fmaxf(a, __shfl_xor(a, 2));
    a = fmaxf(a, __shfl_xor(a, 4));
    a = fmaxf(a, __shfl_xor(a, 8));

    const float descale = a / 6.0f;                         // exact div (ref-match)
    const float e = ceilf(fmaxf(log2f(descale), -127.0f));  // libm log2 (ref-match)
    const int ie = (int)e;
    const float inv_scale = __int_as_float((127 - ie) << 23);     // 2^-e exact
    const float scale = (ie == -127) ? __int_as_float(0x00400000) // 2^-127 subnormal
                                     : __int_as_float((ie + 127) << 23);

    float ys[EPT], cd[EPT];
    float wa[8], wb[8];   // weights of elem i=0 / i=1

#pragma unroll
    for (int i = 0; i < EPT; ++i) {
        float* w = (i == 0) ? wa : wb;        // static after unroll
        const float xs = xe[i] * inv_scale;   // exact: power-of-two multiply
        const float xa = fabsf(xs);

        int ord = 0;
#pragma unroll
        for (int j = 0; j < 7; ++j) ord += (xa > sb[j]) ? 1 : 0;   // exact compares

        const float xac = xa * C;
        float p[7];
#pragma unroll
        for (int j = 0; j < 7; ++j) {
            const float ex = exp2f(cb[j] - xac);        // exp((sb-xa)/tau) via v_exp
            p[j] = __builtin_amdgcn_rcpf(1.0f + ex);    // sigmoid
        }

        w[0] = 1.0f - p[0];
#pragma unroll
        for (int j = 1; j < 7; ++j) w[j] = p[j - 1] - p[j];
        w[7] = p[6];

        float sum = 0.0f;
#pragma unroll
        for (int k = 0; k < 8; ++k) { w[k] = fmaxf(w[k], 0.0f); sum += w[k]; }
        const float inv = __builtin_amdgcn_rcpf(sum + 1e-8f);

        float abs_soft = 0.0f;
#pragma unroll
        for (int k = 0; k < 8; ++k) { w[k] *= inv; abs_soft += w[k] * vt[k]; }

        // abs_hard via cndmask chain off SGPR table values (no LDS)
        float abs_hard = vt[0];
#pragma unroll
        for (int k = 1; k < 8; ++k) abs_hard = (ord == k) ? vt[k] : abs_hard;

        const float abs_mix = abs_soft + (abs_hard - abs_soft);  // faithful ST expr
        ys[i] = ((xs >= 0.0f) ? abs_mix : -abs_mix) * scale;
        cd[i] = (float)(((xs < 0.0f) ? 8 : 0) | ord);
    }

    // y / codes: aligned float2 vector stores
    *reinterpret_cast<float2*>(out + g0)     = make_float2(ys[0], ys[1]);
    *reinterpret_cast<float2*>(out + N + g0) = make_float2(cd[0], cd[1]);
    if ((tid & 15) == 0) out[2 * N + (g0 >> 5)] = e + 127.0f;
    if (blockIdx.x == 0 && tid < 7) {
        float v = sb[0];
#pragma unroll
        for (int j = 1; j < 7; ++j) v = (tid == j) ? sb[j] : v;
        out[2 * N + (N >> 5) + tid] = v;
    }

    // weights: direct register writeback.
    // Block region starts at float index S (S % 4 == 3). Thread t covers
    // S + 16t .. S + 16t + 16 (head float via previous lane / lane-0 rule).
    const long long S = 2 * N + (N >> 5) + 7 + (long long)blockIdx.x * (ELEMS * 8);
    const long long tb = S + 16 * (long long)tid;
    const float nw0 = __shfl_down(wa[0], 1);   // next thread's elem-0 w0
    const int lane = tid & 63;

    *reinterpret_cast<float4*>(out + tb + 1) = make_float4(wa[1], wa[2], wa[3], wa[4]);
    *reinterpret_cast<float4*>(out + tb + 5) = make_float4(wa[5], wa[6], wa[7], wb[0]);
    *reinterpret_cast<float4*>(out + tb + 9) = make_float4(wb[1], wb[2], wb[3], wb[4]);
    if (lane != 63) {
        *reinterpret_cast<float4*>(out + tb + 13) =
            make_float4(wb[5], wb[6], wb[7], nw0);
    } else {   // wave boundary: no valid shfl source
        out[tb + 13] = wb[5];
        out[tb + 14] = wb[6];
        out[tb + 15] = wb[7];
    }
    if (lane == 0) out[tb] = wa[0];   // head float of each wave's span
}

extern "C" void kernel_launch(void* const* d_in, const int* in_sizes, int n_in,
                              void* d_out, int out_size, void* d_ws, size_t ws_size,
                              hipStream_t stream) {
    const float* x      = (const float*)d_in[0];
    const float* delta  = (const float*)d_in[1];
    const float* bounds = (const float*)d_in[2];
    const float* vals   = (const float*)d_in[3];
    float* out = (float*)d_out;
    const long long N = (long long)in_sizes[0];   // 8388608 = 2^23
    const int nblocks = (int)(N / ELEMS);
    fp4_kernel<<<nblocks, BLK, 0, stream>>>(x, delta, bounds, vals, out, N);
}

// Round 4
// 377.986 us; speedup vs baseline: 1.0633x; 1.0633x over previous
//
#include <hip/hip_runtime.h>

#define BLK 256
#define EPT 4                      // elements per thread
#define WLDS (BLK * EPT * 8)       // 8192 floats = 32 KB weight staging

typedef float f32x4 __attribute__((ext_vector_type(4)));

// R1 structure (best measured: 358.3 us) + nontemporal loads/stores.
// All output streams are write-once never-read: nt avoids L2 write-allocate
// (read-for-ownership) traffic, which theory says is the remaining ~2x on the
// write streams. Decision path bit-identical to the passing kernel.
__global__ __launch_bounds__(BLK) void fp4_kernel(
    const float* __restrict__ x,
    const float* __restrict__ delta_raw,
    const float* __restrict__ bounds_base,
    const float* __restrict__ values_table,
    float* __restrict__ out, long long N)
{
    const int tid = threadIdx.x;
    const long long base = (long long)blockIdx.x * (BLK * EPT);
    const long long g0 = base + (long long)(tid * EPT);

    __shared__ float s_vals[8];
    __shared__ __align__(16) float s_w[WLDS];   // XOR-swizzled staging

    if (tid < 8) s_vals[tid] = values_table[tid];

    // wave-uniform scalars
    const float ht = 0.5f * tanhf(delta_raw[0]);
    const float C = 14.426950408889634f;        // (1/TAU) * log2(e)
    float sb[7], cb[7];
#pragma unroll
    for (int j = 0; j < 7; ++j) { sb[j] = bounds_base[j] + ht; cb[j] = sb[j] * C; }
    float vt[8];
#pragma unroll
    for (int k = 0; k < 8; ++k) vt[k] = values_table[k];

    __syncthreads();

    const f32x4 xv = __builtin_nontemporal_load(
        reinterpret_cast<const f32x4*>(x + g0));
    const float xe[EPT] = {xv.x, xv.y, xv.z, xv.w};

    // per-32-block amax: local max of 4, butterfly over the 8-lane group.
    // fmax exactly associative/commutative -> bit-identical to reference.
    float a = fmaxf(fmaxf(fabsf(xe[0]), fabsf(xe[1])),
                    fmaxf(fabsf(xe[2]), fabsf(xe[3])));
    a = fmaxf(a, __shfl_xor(a, 1));
    a = fmaxf(a, __shfl_xor(a, 2));
    a = fmaxf(a, __shfl_xor(a, 4));

    const float descale = a / 6.0f;                         // exact div (ref-match)
    const float e = ceilf(fmaxf(log2f(descale), -127.0f));  // libm log2 (ref-match)
    const int ie = (int)e;
    const float inv_scale = __int_as_float((127 - ie) << 23);     // 2^-e exact
    const float scale = (ie == -127) ? __int_as_float(0x00400000) // 2^-127 subnormal
                                     : __int_as_float((ie + 127) << 23);

    const int wkey = (tid & 7) << 2;
    float ys[EPT], cd[EPT];

#pragma unroll
    for (int i = 0; i < EPT; ++i) {
        const float xs = xe[i] * inv_scale;   // exact: power-of-two multiply
        const float xa = fabsf(xs);

        int ord = 0;
#pragma unroll
        for (int j = 0; j < 7; ++j) ord += (xa > sb[j]) ? 1 : 0;   // exact compares

        const float xac = xa * C;
        float p[7];
#pragma unroll
        for (int j = 0; j < 7; ++j) {
            const float ex = exp2f(cb[j] - xac);        // exp((sb-xa)/tau) via v_exp
            p[j] = __builtin_amdgcn_rcpf(1.0f + ex);    // sigmoid
        }

        float w[8];
        w[0] = 1.0f - p[0];
#pragma unroll
        for (int j = 1; j < 7; ++j) w[j] = p[j - 1] - p[j];
        w[7] = p[6];

        float sum = 0.0f;
#pragma unroll
        for (int k = 0; k < 8; ++k) { w[k] = fmaxf(w[k], 0.0f); sum += w[k]; }
        const float inv = __builtin_amdgcn_rcpf(sum + 1e-8f);

        float abs_soft = 0.0f;
#pragma unroll
        for (int k = 0; k < 8; ++k) { w[k] *= inv; abs_soft += w[k] * vt[k]; }

        const float abs_hard = s_vals[ord];                      // LDS dynamic index
        const float abs_mix = abs_soft + (abs_hard - abs_soft);  // faithful ST expr
        ys[i] = ((xs >= 0.0f) ? abs_mix : -abs_mix) * scale;
        cd[i] = (float)(((xs < 0.0f) ? 8 : 0) | ord);

        // stage weights, XOR-swizzled: physical = logical ^ ((owner_thread&7)<<2)
        const int f = (tid * EPT + i) * 8;
        *reinterpret_cast<float4*>(&s_w[(f + 0) ^ wkey]) =
            make_float4(w[0], w[1], w[2], w[3]);
        *reinterpret_cast<float4*>(&s_w[(f + 4) ^ wkey]) =
            make_float4(w[4], w[5], w[6], w[7]);
    }

    // y / codes: aligned 16B nontemporal vector stores
    {
        f32x4 vy = {ys[0], ys[1], ys[2], ys[3]};
        f32x4 vc = {cd[0], cd[1], cd[2], cd[3]};
        __builtin_nontemporal_store(vy, reinterpret_cast<f32x4*>(out + g0));
        __builtin_nontemporal_store(vc, reinterpret_cast<f32x4*>(out + N + g0));
    }
    if ((tid & 7) == 0)
        __builtin_nontemporal_store(e + 127.0f, out + 2 * N + (g0 >> 5));
    if (blockIdx.x == 0 && tid < 7) out[2 * N + (N >> 5) + tid] = sb[tid];

    __syncthreads();

    // coalesced scalar readback (weights base misaligned by 3 floats -> dword
    // stores, always aligned). Logical g = tid + 256k; owner = g>>5;
    // physical = g ^ ((owner&7)<<2). (tid>>5)&7 is k-invariant -> hoist.
    const long long wbase = 2 * N + (N >> 5) + 7 + (long long)blockIdx.x * WLDS;
    const int rbase = tid ^ (((tid >> 5) & 7) << 2);
#pragma unroll
    for (int k = 0; k < 32; ++k) {
        __builtin_nontemporal_store(s_w[rbase + (k << 8)],
                                    out + wbase + tid + (k << 8));
    }
}

extern "C" void kernel_launch(void* const* d_in, const int* in_sizes, int n_in,
                              void* d_out, int out_size, void* d_ws, size_t ws_size,
                              hipStream_t stream) {
    const float* x      = (const float*)d_in[0];
    const float* delta  = (const float*)d_in[1];
    const float* bounds = (const float*)d_in[2];
    const float* vals   = (const float*)d_in[3];
    float* out = (float*)d_out;
    const long long N = (long long)in_sizes[0];   // 8388608 = 2^23
    const int nblocks = (int)(N / (BLK * EPT));
    fp4_kernel<<<nblocks, BLK, 0, stream>>>(x, delta, bounds, vals, out, N);
}

// Round 5
// 358.762 us; speedup vs baseline: 1.1202x; 1.0536x over previous
//
#include <hip/hip_runtime.h>

#define BLK 256
#define EPT 4                      // elements per thread
#define WLDS (BLK * EPT * 8)       // 8192 floats = 32 KB weight staging

// R1 structure (best measured: 358.3 us) + exp-hoist:
//   exp2(cb_j - xa*C) == K_j * exp2(-xa*C),  K_j = exp2(cb_j) wave-uniform.
// -> 1 v_exp per element instead of 7, and (1 + K_j*E) fuses to one v_fma.
// Decision path (amax order, a/6.0f exact div, libm log2f, ceilf, bit-built
// 2^-e, exact bound compares) is bit-identical to the passing kernel.
__global__ __launch_bounds__(BLK) void fp4_kernel(
    const float* __restrict__ x,
    const float* __restrict__ delta_raw,
    const float* __restrict__ bounds_base,
    const float* __restrict__ values_table,
    float* __restrict__ out, long long N)
{
    const int tid = threadIdx.x;
    const long long base = (long long)blockIdx.x * (BLK * EPT);
    const long long g0 = base + (long long)(tid * EPT);

    __shared__ float s_vals[8];
    __shared__ __align__(16) float s_w[WLDS];   // XOR-swizzled staging

    if (tid < 8) s_vals[tid] = values_table[tid];

    // wave-uniform scalars
    float ht = 0.5f * tanhf(delta_raw[0]);
    ht = __int_as_float(__builtin_amdgcn_readfirstlane(__float_as_int(ht)));
    const float C  = 14.426950408889634f;       // (1/TAU) * log2(e)
    const float Cn = -14.426950408889634f;
    float sb[7], Kj[7];
#pragma unroll
    for (int j = 0; j < 7; ++j) {
        sb[j] = bounds_base[j] + ht;
        float k = exp2f(sb[j] * C);             // K_j = exp2(cb_j), uniform
        Kj[j] = __int_as_float(__builtin_amdgcn_readfirstlane(__float_as_int(k)));
    }
    float vt[8];
#pragma unroll
    for (int k = 0; k < 8; ++k) vt[k] = values_table[k];

    __syncthreads();

    const float4 xv = *reinterpret_cast<const float4*>(x + g0);
    const float xe[EPT] = {xv.x, xv.y, xv.z, xv.w};

    // per-32-block amax: local max of 4, butterfly over the 8-lane group.
    // fmax exactly associative/commutative -> bit-identical to reference.
    float a = fmaxf(fmaxf(fabsf(xe[0]), fabsf(xe[1])),
                    fmaxf(fabsf(xe[2]), fabsf(xe[3])));
    a = fmaxf(a, __shfl_xor(a, 1));
    a = fmaxf(a, __shfl_xor(a, 2));
    a = fmaxf(a, __shfl_xor(a, 4));

    const float descale = a / 6.0f;                         // exact div (ref-match)
    const float e = ceilf(fmaxf(log2f(descale), -127.0f));  // libm log2 (ref-match)
    const int ie = (int)e;
    const float inv_scale = __int_as_float((127 - ie) << 23);     // 2^-e exact
    const float scale = (ie == -127) ? __int_as_float(0x00400000) // 2^-127 subnormal
                                     : __int_as_float((ie + 127) << 23);

    const int wkey = (tid & 7) << 2;
    float ys[EPT], cd[EPT];

#pragma unroll
    for (int i = 0; i < EPT; ++i) {
        const float xs = xe[i] * inv_scale;   // exact: power-of-two multiply
        const float xa = fabsf(xs);

        int ord = 0;
#pragma unroll
        for (int j = 0; j < 7; ++j) ord += (xa > sb[j]) ? 1 : 0;   // exact compares

        const float E = exp2f(xa * Cn);       // exp2(-xa*C): ONE v_exp per element
        float p[7];
#pragma unroll
        for (int j = 0; j < 7; ++j) {
            // sigmoid((xa-sb_j)/tau) = 1 / (1 + K_j * E)
            p[j] = __builtin_amdgcn_rcpf(fmaf(Kj[j], E, 1.0f));
        }

        float w[8];
        w[0] = 1.0f - p[0];
#pragma unroll
        for (int j = 1; j < 7; ++j) w[j] = p[j - 1] - p[j];
        w[7] = p[6];

        float sum = 0.0f;
#pragma unroll
        for (int k = 0; k < 8; ++k) { w[k] = fmaxf(w[k], 0.0f); sum += w[k]; }
        const float inv = __builtin_amdgcn_rcpf(sum + 1e-8f);

        float abs_soft = 0.0f;
#pragma unroll
        for (int k = 0; k < 8; ++k) { w[k] *= inv; abs_soft += w[k] * vt[k]; }

        const float abs_hard = s_vals[ord];                      // LDS dynamic index
        const float abs_mix = abs_soft + (abs_hard - abs_soft);  // faithful ST expr
        ys[i] = ((xs >= 0.0f) ? abs_mix : -abs_mix) * scale;
        cd[i] = (float)(((xs < 0.0f) ? 8 : 0) | ord);

        // stage weights, XOR-swizzled: physical = logical ^ ((owner_thread&7)<<2)
        const int f = (tid * EPT + i) * 8;
        *reinterpret_cast<float4*>(&s_w[(f + 0) ^ wkey]) =
            make_float4(w[0], w[1], w[2], w[3]);
        *reinterpret_cast<float4*>(&s_w[(f + 4) ^ wkey]) =
            make_float4(w[4], w[5], w[6], w[7]);
    }

    // y / codes: aligned float4 vector stores
    *reinterpret_cast<float4*>(out + g0)     = make_float4(ys[0], ys[1], ys[2], ys[3]);
    *reinterpret_cast<float4*>(out + N + g0) = make_float4(cd[0], cd[1], cd[2], cd[3]);
    if ((tid & 7) == 0) out[2 * N + (g0 >> 5)] = e + 127.0f;
    if (blockIdx.x == 0 && tid < 7) {
        float v = sb[0];
#pragma unroll
        for (int j = 1; j < 7; ++j) v = (tid == j) ? sb[j] : v;
        out[2 * N + (N >> 5) + tid] = v;
    }

    __syncthreads();

    // coalesced scalar readback (weights base misaligned by 3 floats -> dword
    // stores, always aligned). Logical g = tid + 256k; owner = g>>5;
    // physical = g ^ ((owner&7)<<2). (tid>>5)&7 is k-invariant -> hoist.
    const long long wbase = 2 * N + (N >> 5) + 7 + (long long)blockIdx.x * WLDS;
    const int rbase = tid ^ (((tid >> 5) & 7) << 2);
#pragma unroll
    for (int k = 0; k < 32; ++k) {
        out[wbase + tid + (k << 8)] = s_w[rbase + (k << 8)];
    }
}

extern "C" void kernel_launch(void* const* d_in, const int* in_sizes, int n_in,
                              void* d_out, int out_size, void* d_ws, size_t ws_size,
                              hipStream_t stream) {
    const float* x      = (const float*)d_in[0];
    const float* delta  = (const float*)d_in[1];
    const float* bounds = (const float*)d_in[2];
    const float* vals   = (const float*)d_in[3];
    float* out = (float*)d_out;
    const long long N = (long long)in_sizes[0];   // 8388608 = 2^23
    const int nblocks = (int)(N / (BLK * EPT));
    fp4_kernel<<<nblocks, BLK, 0, stream>>>(x, delta, bounds, vals, out, N);
}